// Round 5
// baseline (12139.045 us; speedup 1.0000x reference)
//
#include <hip/hip_runtime.h>
#include <hip/hip_bf16.h>

// Problem constants
#define BATCH   64
#define SEQ     512
#define DMODEL  256
#define HIDDEN  512
#define G3      1536      // 3*HIDDEN
#define NBLK    128       // scan blocks; 512 hidden units / 128 = 4 units/block
#define UPB     4         // units per block
#define CPB     12        // Wh columns per block (3 gates * UPB)

typedef unsigned long long u64;
typedef unsigned int u32;

// ---------------------------------------------------------------------------
// Pack Wh slices: whp[blk][c][k] = Wh[k][ g*512 + blk*4 + u ]  (c = g*4+u)
// Contiguous in k so the scan kernel's wave-uniform weight reads scalarize
// (s_load from hot L2; nothing in the scan loop invalidates L2).
// ---------------------------------------------------------------------------
__global__ __launch_bounds__(512) void prep_wh(const float* __restrict__ Wh,
                                               float* __restrict__ whp) {
    int t = blockIdx.x * 512 + threadIdx.x;      // 0 .. 786431
    int k   = t & 511;
    int cb  = t >> 9;          // blk*12 + c
    int c   = cb % 12;
    int blk = cb / 12;
    int u = c & 3, g = c >> 2;
    whp[t] = Wh[(long)k * G3 + g * HIDDEN + blk * UPB + u];
}

// ---------------------------------------------------------------------------
// xg GEMM, TRANSPOSED output: xgS[col][s][b] = emb[ids[b][s]] . Wx[:,col] + bx[col]
// so the scan's per-step gate reads are coalesced (b fastest).
// ---------------------------------------------------------------------------
__global__ __launch_bounds__(256) void xg_gemm(const int* __restrict__ ids,
                                               const float* __restrict__ emb,
                                               const float* __restrict__ Wx,
                                               const float* __restrict__ bx,
                                               float* __restrict__ xgS) {
    __shared__ float Es[64][68];   // Es[k][b], padded
    __shared__ float Ws[64][68];   // Ws[k][c], padded
    __shared__ int   sids[64];

    const int tid = threadIdx.x;
    const int nb = blockIdx.x;     // col tile 0..23
    const int s  = blockIdx.y;     // timestep 0..511
    const int tn = tid & 15;
    const int tm = tid >> 4;

    if (tid < 64) sids[tid] = ids[tid * SEQ + s];   // id for batch=tid at step s
    __syncthreads();

    float acc[4][4];               // acc[i=col][j=b]
#pragma unroll
    for (int i = 0; i < 4; ++i)
#pragma unroll
        for (int j = 0; j < 4; ++j) acc[i][j] = 0.f;

    for (int kb = 0; kb < 256; kb += 64) {
#pragma unroll
        for (int p = 0; p < 4; ++p) {
            int b = p * 16 + tm;
            float4 av = *(const float4*)(emb + (long)sids[b] * DMODEL + kb + tn * 4);
            Es[tn * 4 + 0][b] = av.x;
            Es[tn * 4 + 1][b] = av.y;
            Es[tn * 4 + 2][b] = av.z;
            Es[tn * 4 + 3][b] = av.w;
            int krow = p * 16 + tm;
            float4 wv = *(const float4*)(Wx + (long)(kb + krow) * G3 + nb * 64 + tn * 4);
            *(float4*)&Ws[krow][tn * 4] = wv;
        }
        __syncthreads();
#pragma unroll
        for (int k = 0; k < 64; ++k) {
            float4 w4 = *(const float4*)&Ws[k][tm * 4];
            float4 e4 = *(const float4*)&Es[k][tn * 4];
            float ww[4] = {w4.x, w4.y, w4.z, w4.w};
            float ee[4] = {e4.x, e4.y, e4.z, e4.w};
#pragma unroll
            for (int i = 0; i < 4; ++i)
#pragma unroll
                for (int j = 0; j < 4; ++j)
                    acc[i][j] = fmaf(ww[i], ee[j], acc[i][j]);
        }
        __syncthreads();
    }

#pragma unroll
    for (int i = 0; i < 4; ++i) {
        int col = nb * 64 + tm * 4 + i;
        float bxi = bx[col];
        float4 o;
        o.x = acc[i][0] + bxi;
        o.y = acc[i][1] + bxi;
        o.z = acc[i][2] + bxi;
        o.w = acc[i][3] + bxi;
        *(float4*)(xgS + (long)col * (SEQ * BATCH) + s * 64 + tn * 4) = o;
    }
}

// ---------------------------------------------------------------------------
// GRU scan v5: tagged-h handshake (v3) + PIPELINED bulk h loads.
// v2/v3/v4 all plateaued at ~11-13 us/step; the common element was 64
// per-lane __hip_atomic_load's, which the compiler serializes (one waitcnt
// per atomic) -> 64 x ~450cyc = the whole step time. Here the bulk pass
// uses plain volatile u64 loads (ordinary global_load_dwordx2: issued
// back-to-back, single waitcnt at first use), then a verify loop retries
// ONLY stale-tagged entries with coherent agent-scope atomic loads.
// Correctness does not depend on L2 invalidation: any stale value fails
// the tag check and is re-read at the coherence point.
// ABA-safe (v3 argument): a block writes tag t+2 only after consuming all
// tag-(t+1) values, so slot[t&1] never holds a tag > t before consumption.
// Deadlock-free: 128 blocks co-resident (<=256 CUs, one kernel).
// ---------------------------------------------------------------------------
__global__ __launch_bounds__(512, 2) void gru_scan(const float* __restrict__ whp,
                                                   const float* __restrict__ xgS,
                                                   const float* __restrict__ bh,
                                                   u64* hp) {
    const int tid = threadIdx.x;
    const int blk = blockIdx.x;
    const int b   = tid & 63;                                 // lane = batch
    const int wu  = __builtin_amdgcn_readfirstlane(tid >> 6); // wave 0..7

    __shared__ float part[8][CPB][64];   // 24 KB partial sums
    __shared__ float hl[UPB][64];        // this block's own h slice (hprev)

    const float* wb = whp + blk * (CPB * HIDDEN) + wu * 64;   // + c*512 + i

    const int gu = tid >> 6;
    int jg = 0;
    float bhr = 0.f, bhz = 0.f, bhn = 0.f;
    const float* xr_p = nullptr; const float* xz_p = nullptr; const float* xn_p = nullptr;
    if (tid < 256) {
        jg  = blk * UPB + gu;
        bhr = bh[jg];
        bhz = bh[HIDDEN + jg];
        bhn = bh[2 * HIDDEN + jg];
        xr_p = xgS + (long)jg * (SEQ * BATCH) + b;
        xz_p = xgS + (long)(HIDDEN + jg) * (SEQ * BATCH) + b;
        xn_p = xgS + (long)(2 * HIDDEN + jg) * (SEQ * BATCH) + b;
        hl[gu][b] = 0.f;                 // h0 = 0
    }
    __syncthreads();

#pragma unroll 1
    for (int t = 0; t < SEQ; ++t) {
        u64* hcur = hp + (t & 1) * (HIDDEN * BATCH);
        u64* hnxt = hp + ((t + 1) & 1) * (HIDDEN * BATCH);

        // coalesced gate-input loads (xgS[col][t][b]); read-only, cached
        float xr = 0.f, xz = 0.f, xn = 0.f, hprev = 0.f;
        if (tid < 256) {
            xr = xr_p[t * 64];
            xz = xz_p[t * 64];
            xn = xn_p[t * 64];
            hprev = hl[gu][b];
        }

        if (t > 0) {
            const u64* hc = hcur + (wu * 64) * 64 + b;
            const u32 want = (u32)t;
            u64 v[64];
            // bulk pass: plain volatile loads -> pipelined global_load_dwordx2
#pragma unroll
            for (int i = 0; i < 64; ++i)
                v[i] = ((const volatile u64*)hc)[(long)i * 64];
            // verify tags; retry only stale entries at the coherence point
            for (;;) {
                bool ok = true;
#pragma unroll
                for (int i = 0; i < 64; ++i) {
                    if ((u32)(v[i] >> 32) != want) {
                        ok = false;
                        v[i] = __hip_atomic_load(hc + (long)i * 64,
                                                 __ATOMIC_RELAXED,
                                                 __HIP_MEMORY_SCOPE_AGENT);
                    }
                }
                if (__all(ok)) break;
            }

            float acc[CPB];
#pragma unroll
            for (int c = 0; c < CPB; ++c) acc[c] = 0.f;
#pragma unroll
            for (int i = 0; i < 64; ++i) {
                float hv = __uint_as_float((u32)v[i]);
#pragma unroll
                for (int c = 0; c < CPB; ++c)
                    acc[c] = fmaf(hv, wb[c * HIDDEN + i], acc[c]);
            }
#pragma unroll
            for (int c = 0; c < CPB; ++c) part[wu][c][b] = acc[c];
        } else {
            // h0 == 0 => hg = bh
#pragma unroll
            for (int c = 0; c < CPB; ++c) part[wu][c][b] = 0.f;
        }
        __syncthreads();                                   // partials ready

        if (tid < 256) {
            float hgr = bhr, hgz = bhz, hgn = bhn;
#pragma unroll
            for (int ww = 0; ww < 8; ++ww) {
                hgr += part[ww][gu][b];
                hgz += part[ww][4 + gu][b];
                hgn += part[ww][8 + gu][b];
            }
            float r  = 1.f / (1.f + expf(-(xr + hgr)));
            float z  = 1.f / (1.f + expf(-(xz + hgz)));
            float nn = tanhf(xn + r * hgn);
            float hnew = (1.f - z) * nn + z * hprev;
            u64 pk = ((u64)(u32)(t + 1) << 32) | (u64)__float_as_uint(hnew);
            // agent-scope write-through: lands at the coherence point and
            // (empirically) invalidates remote L2 copies -> fast path fresh
            __hip_atomic_store(&hnxt[jg * 64 + b], pk, __ATOMIC_RELAXED,
                               __HIP_MEMORY_SCOPE_AGENT);
            hl[gu][b] = hnew;
        }
        // protects part[]/hl[] reuse next iteration
        __syncthreads();
    }
}

// ---------------------------------------------------------------------------
// head: logits[b][n] = sum_k h[k][b] * Wo[k][n] + bo[n]
// Final h (tag 512) sits in slot 0 of hp; value is the low 32 bits.
// ---------------------------------------------------------------------------
__global__ void head_kernel(const u64* __restrict__ hT,
                            const float* __restrict__ Wo,
                            const float* __restrict__ bo,
                            float* __restrict__ out) {
    int tid = threadIdx.x;        // 128 threads
    int b = tid >> 1, n = tid & 1;
    float acc = bo[n];
#pragma unroll 8
    for (int k = 0; k < HIDDEN; ++k)
        acc = fmaf(__uint_as_float((u32)hT[k * 64 + b]), Wo[k * 2 + n], acc);
    out[b * 2 + n] = acc;
}

// ---------------------------------------------------------------------------
extern "C" void kernel_launch(void* const* d_in, const int* in_sizes, int n_in,
                              void* d_out, int out_size, void* d_ws, size_t ws_size,
                              hipStream_t stream) {
    (void)in_sizes; (void)n_in; (void)out_size; (void)ws_size;
    const int*   ids = (const int*)  d_in[0];
    const float* emb = (const float*)d_in[1];
    const float* Wx  = (const float*)d_in[2];
    const float* Wh  = (const float*)d_in[3];
    const float* bx  = (const float*)d_in[4];
    const float* bh  = (const float*)d_in[5];
    const float* Wo  = (const float*)d_in[6];
    const float* bo  = (const float*)d_in[7];
    float* out = (float*)d_out;

    char* ws = (char*)d_ws;
    // ws layout: [hp 2*512*64 u64 = 512KB][whp 3MB][xgS 201MB]
    // hp needs NO init: poison 0xAAAAAAAA never matches a tag in [1,512].
    u64*   hpd  = (u64*)ws;
    float* whp  = (float*)(ws + 2 * HIDDEN * BATCH * sizeof(u64));
    float* xgS  = (float*)(ws + 2 * HIDDEN * BATCH * sizeof(u64) + NBLK * CPB * HIDDEN * 4);

    prep_wh<<<dim3(1536), dim3(512), 0, stream>>>(Wh, whp);
    xg_gemm<<<dim3(24, 512), dim3(256), 0, stream>>>(ids, emb, Wx, bx, xgS);
    gru_scan<<<dim3(NBLK), dim3(512), 0, stream>>>(whp, xgS, bh, hpd);
    head_kernel<<<dim3(1), dim3(128), 0, stream>>>(hpd, Wo, bo, out);
}

// Round 6
// 8583.057 us; speedup vs baseline: 1.4143x; 1.4143x over previous
//
#include <hip/hip_runtime.h>
#include <hip/hip_bf16.h>

// Problem constants
#define BATCH   64
#define SEQ     512
#define DMODEL  256
#define HIDDEN  512
#define G3      1536      // 3*HIDDEN
#define NBLK    128       // scan blocks; 512 hidden units / 128 = 4 units/block
#define UPB     4         // units per block
#define CPB     12        // Wh columns per block (3 gates * UPB)

typedef unsigned long long u64;
typedef unsigned int u32;

// ---------------------------------------------------------------------------
// Pack Wh slices: whp[blk][c][k] = Wh[k][ g*512 + blk*4 + u ]  (c = g*4+u)
// Contiguous in k so the scan kernel's wave-uniform weight reads scalarize
// (s_load from hot L2; nothing in the scan loop invalidates L2).
// ---------------------------------------------------------------------------
__global__ __launch_bounds__(512) void prep_wh(const float* __restrict__ Wh,
                                               float* __restrict__ whp) {
    int t = blockIdx.x * 512 + threadIdx.x;      // 0 .. 786431
    int k   = t & 511;
    int cb  = t >> 9;          // blk*12 + c
    int c   = cb % 12;
    int blk = cb / 12;
    int u = c & 3, g = c >> 2;
    whp[t] = Wh[(long)k * G3 + g * HIDDEN + blk * UPB + u];
}

// ---------------------------------------------------------------------------
// Zero barrier flags with agent-scope stores (the scan polls with
// L2-bypassing loads; plain memset could leave zeros dirty in one L2).
// ---------------------------------------------------------------------------
__global__ void init_flags(unsigned* flags) {
    __hip_atomic_store(&flags[threadIdx.x], 0u, __ATOMIC_RELAXED,
                       __HIP_MEMORY_SCOPE_AGENT);
}

// ---------------------------------------------------------------------------
// xg GEMM, TRANSPOSED output: xgS[col][s][b] = emb[ids[b][s]] . Wx[:,col] + bx[col]
// so the scan's per-step gate reads are coalesced (b fastest).
// ---------------------------------------------------------------------------
__global__ __launch_bounds__(256) void xg_gemm(const int* __restrict__ ids,
                                               const float* __restrict__ emb,
                                               const float* __restrict__ Wx,
                                               const float* __restrict__ bx,
                                               float* __restrict__ xgS) {
    __shared__ float Es[64][68];   // Es[k][b], padded
    __shared__ float Ws[64][68];   // Ws[k][c], padded
    __shared__ int   sids[64];

    const int tid = threadIdx.x;
    const int nb = blockIdx.x;     // col tile 0..23
    const int s  = blockIdx.y;     // timestep 0..511
    const int tn = tid & 15;
    const int tm = tid >> 4;

    if (tid < 64) sids[tid] = ids[tid * SEQ + s];   // id for batch=tid at step s
    __syncthreads();

    float acc[4][4];               // acc[i=col][j=b]
#pragma unroll
    for (int i = 0; i < 4; ++i)
#pragma unroll
        for (int j = 0; j < 4; ++j) acc[i][j] = 0.f;

    for (int kb = 0; kb < 256; kb += 64) {
#pragma unroll
        for (int p = 0; p < 4; ++p) {
            int b = p * 16 + tm;
            float4 av = *(const float4*)(emb + (long)sids[b] * DMODEL + kb + tn * 4);
            Es[tn * 4 + 0][b] = av.x;
            Es[tn * 4 + 1][b] = av.y;
            Es[tn * 4 + 2][b] = av.z;
            Es[tn * 4 + 3][b] = av.w;
            int krow = p * 16 + tm;
            float4 wv = *(const float4*)(Wx + (long)(kb + krow) * G3 + nb * 64 + tn * 4);
            *(float4*)&Ws[krow][tn * 4] = wv;
        }
        __syncthreads();
#pragma unroll
        for (int k = 0; k < 64; ++k) {
            float4 w4 = *(const float4*)&Ws[k][tm * 4];
            float4 e4 = *(const float4*)&Es[k][tn * 4];
            float ww[4] = {w4.x, w4.y, w4.z, w4.w};
            float ee[4] = {e4.x, e4.y, e4.z, e4.w};
#pragma unroll
            for (int i = 0; i < 4; ++i)
#pragma unroll
                for (int j = 0; j < 4; ++j)
                    acc[i][j] = fmaf(ww[i], ee[j], acc[i][j]);
        }
        __syncthreads();
    }

#pragma unroll
    for (int i = 0; i < 4; ++i) {
        int col = nb * 64 + tm * 4 + i;
        float bxi = bx[col];
        float4 o;
        o.x = acc[i][0] + bxi;
        o.y = acc[i][1] + bxi;
        o.z = acc[i][2] + bxi;
        o.w = acc[i][3] + bxi;
        *(float4*)(xgS + (long)col * (SEQ * BATCH) + s * 64 + tn * 4) = o;
    }
}

// ---------------------------------------------------------------------------
// GRU scan v6 = v4's single-poller flag barrier + PLAIN pipelined bulk loads
// of tagged u64 h.
// Evidence so far: v3 (64 atomic loads) 13.2us/step, v4 (same loads, flag
// barrier) 10.9, v5 (64 volatile loads) 22.9 -> the bulk h read serializes
// one-load-at-a-time under atomic OR volatile lowering; the handshake was
// never dominant. Plain loads are the only flavor the compiler pipelines
// (64 back-to-back global_load_dwordx2, one waitcnt at use).
// Correctness: each h value carries its step tag. After the flag barrier
// the data is logically ready; if a plain load still sees a stale cached
// value, the tag check catches it and re-reads with an agent-scope atomic
// (L1/L2-bypassing). No reliance on unverified invalidation behavior, and
// no retry storm (retries should be ~0; pollers are 1 wave/block).
// Deadlock-free: 128 blocks co-resident (<=256 CUs, one kernel).
// ---------------------------------------------------------------------------
__global__ __launch_bounds__(512, 2) void gru_scan(const float* __restrict__ whp,
                                                   const float* __restrict__ xgS,
                                                   const float* __restrict__ bh,
                                                   u64* hp,
                                                   unsigned* flags) {
    const int tid = threadIdx.x;
    const int blk = blockIdx.x;
    const int b   = tid & 63;                                 // lane = batch
    const int wu  = __builtin_amdgcn_readfirstlane(tid >> 6); // wave 0..7

    __shared__ float part[8][CPB][64];   // 24 KB partial sums
    __shared__ float hl[UPB][64];        // this block's own h slice (hprev)

    const float* wb = whp + blk * (CPB * HIDDEN) + wu * 64;   // + c*512 + i

    const int gu = tid >> 6;
    int jg = 0;
    float bhr = 0.f, bhz = 0.f, bhn = 0.f;
    const float* xr_p = nullptr; const float* xz_p = nullptr; const float* xn_p = nullptr;
    if (tid < 256) {
        jg  = blk * UPB + gu;
        bhr = bh[jg];
        bhz = bh[HIDDEN + jg];
        bhn = bh[2 * HIDDEN + jg];
        xr_p = xgS + (long)jg * (SEQ * BATCH) + b;
        xz_p = xgS + (long)(HIDDEN + jg) * (SEQ * BATCH) + b;
        xn_p = xgS + (long)(2 * HIDDEN + jg) * (SEQ * BATCH) + b;
        hl[gu][b] = 0.f;                 // h0 = 0
    }
    __syncthreads();

#pragma unroll 1
    for (int t = 0; t < SEQ; ++t) {
        u64* hcur = hp + (t & 1) * (HIDDEN * BATCH);
        u64* hnxt = hp + ((t + 1) & 1) * (HIDDEN * BATCH);

        // coalesced gate-input loads (xgS[col][t][b]); read-only, cached
        float xr = 0.f, xz = 0.f, xn = 0.f, hprev = 0.f;
        if (tid < 256) {
            xr = xr_p[t * 64];
            xz = xz_p[t * 64];
            xn = xn_p[t * 64];
            hprev = hl[gu][b];
        }

        if (t > 0) {
            const u64* hc = hcur + (wu * 64) * 64 + b;
            const u32 want = (u32)t;
            u64 v[64];
            // bulk pass: PLAIN loads -> pipelined global_load_dwordx2,
            // single waitcnt at first use
#pragma unroll
            for (int i = 0; i < 64; ++i)
                v[i] = hc[(long)i * 64];
            // safety net: retry stale entries at the coherence point
            // (expected 0 iterations — flag barrier already passed)
            for (;;) {
                bool ok = true;
#pragma unroll
                for (int i = 0; i < 64; ++i) {
                    if ((u32)(v[i] >> 32) != want) {
                        ok = false;
                        v[i] = __hip_atomic_load(hc + (long)i * 64,
                                                 __ATOMIC_RELAXED,
                                                 __HIP_MEMORY_SCOPE_AGENT);
                    }
                }
                if (__all(ok)) break;
            }

            float acc[CPB];
#pragma unroll
            for (int c = 0; c < CPB; ++c) acc[c] = 0.f;
#pragma unroll
            for (int i = 0; i < 64; ++i) {
                float hv = __uint_as_float((u32)v[i]);
#pragma unroll
                for (int c = 0; c < CPB; ++c)
                    acc[c] = fmaf(hv, wb[c * HIDDEN + i], acc[c]);
            }
#pragma unroll
            for (int c = 0; c < CPB; ++c) part[wu][c][b] = acc[c];
        } else {
            // h0 == 0 => hg = bh
#pragma unroll
            for (int c = 0; c < CPB; ++c) part[wu][c][b] = 0.f;
        }
        __syncthreads();                                   // sync1: partials ready

        if (tid < 256) {
            float hgr = bhr, hgz = bhz, hgn = bhn;
#pragma unroll
            for (int ww = 0; ww < 8; ++ww) {
                hgr += part[ww][gu][b];
                hgz += part[ww][4 + gu][b];
                hgn += part[ww][8 + gu][b];
            }
            float r  = 1.f / (1.f + expf(-(xr + hgr)));
            float z  = 1.f / (1.f + expf(-(xz + hgz)));
            float nn = tanhf(xn + r * hgn);
            float hnew = (1.f - z) * nn + z * hprev;
            u64 pk = ((u64)(u32)(t + 1) << 32) | (u64)__float_as_uint(hnew);
            __hip_atomic_store(&hnxt[jg * 64 + b], pk, __ATOMIC_RELAXED,
                               __HIP_MEMORY_SCOPE_AGENT);
            hl[gu][b] = hnew;
        }
        __syncthreads();                                   // sync2: drains h stores

        if (t < SEQ - 1) {
            if (tid == 0)
                __hip_atomic_store(&flags[blk], (unsigned)(t + 1),
                                   __ATOMIC_RELAXED, __HIP_MEMORY_SCOPE_AGENT);
            if (wu == 0) {
                // the ONLY polling wave in this block
                const unsigned tgt = (unsigned)(t + 1);
                for (;;) {
                    unsigned f0 = __hip_atomic_load(&flags[b], __ATOMIC_RELAXED,
                                                    __HIP_MEMORY_SCOPE_AGENT);
                    unsigned f1 = __hip_atomic_load(&flags[64 + b], __ATOMIC_RELAXED,
                                                    __HIP_MEMORY_SCOPE_AGENT);
                    if (__all(f0 >= tgt && f1 >= tgt)) break;
                    __builtin_amdgcn_s_sleep(1);
                }
            }
            __syncthreads();                               // sync3: release
            __builtin_amdgcn_fence(__ATOMIC_ACQUIRE, "workgroup"); // compiler order only
        }
    }
}

// ---------------------------------------------------------------------------
// head: logits[b][n] = sum_k h[k][b] * Wo[k][n] + bo[n]
// Final h (tag 512) sits in slot 0 of hp; value is the low 32 bits.
// ---------------------------------------------------------------------------
__global__ void head_kernel(const u64* __restrict__ hT,
                            const float* __restrict__ Wo,
                            const float* __restrict__ bo,
                            float* __restrict__ out) {
    int tid = threadIdx.x;        // 128 threads
    int b = tid >> 1, n = tid & 1;
    float acc = bo[n];
#pragma unroll 8
    for (int k = 0; k < HIDDEN; ++k)
        acc = fmaf(__uint_as_float((u32)hT[k * 64 + b]), Wo[k * 2 + n], acc);
    out[b * 2 + n] = acc;
}

// ---------------------------------------------------------------------------
extern "C" void kernel_launch(void* const* d_in, const int* in_sizes, int n_in,
                              void* d_out, int out_size, void* d_ws, size_t ws_size,
                              hipStream_t stream) {
    (void)in_sizes; (void)n_in; (void)out_size; (void)ws_size;
    const int*   ids = (const int*)  d_in[0];
    const float* emb = (const float*)d_in[1];
    const float* Wx  = (const float*)d_in[2];
    const float* Wh  = (const float*)d_in[3];
    const float* bx  = (const float*)d_in[4];
    const float* bh  = (const float*)d_in[5];
    const float* Wo  = (const float*)d_in[6];
    const float* bo  = (const float*)d_in[7];
    float* out = (float*)d_out;

    char* ws = (char*)d_ws;
    // ws layout: [flags 1KB][hp 2*512*64 u64 = 512KB][whp 3MB][xgS 201MB]
    // hp needs NO init: poison 0xAAAAAAAA never matches a tag in [1,512].
    unsigned* flags = (unsigned*)ws;
    u64*   hpd  = (u64*)(ws + 1024);
    float* whp  = (float*)(ws + 1024 + 2 * HIDDEN * BATCH * sizeof(u64));
    float* xgS  = (float*)(ws + 1024 + 2 * HIDDEN * BATCH * sizeof(u64)
                           + NBLK * CPB * HIDDEN * 4);

    init_flags<<<dim3(1), dim3(NBLK), 0, stream>>>(flags);
    prep_wh<<<dim3(1536), dim3(512), 0, stream>>>(Wh, whp);
    xg_gemm<<<dim3(24, 512), dim3(256), 0, stream>>>(ids, emb, Wx, bx, xgS);
    gru_scan<<<dim3(NBLK), dim3(512), 0, stream>>>(whp, xgS, bh, hpd, flags);
    head_kernel<<<dim3(1), dim3(128), 0, stream>>>(hpd, Wo, bo, out);
}

// Round 7
// 6266.908 us; speedup vs baseline: 1.9370x; 1.3696x over previous
//
#include <hip/hip_runtime.h>
#include <hip/hip_bf16.h>

// Problem constants
#define BATCH   64
#define SEQ     512
#define DMODEL  256
#define HIDDEN  512
#define G3      1536      // 3*HIDDEN
#define NBLK    128       // scan blocks; 512 hidden units / 128 = 4 units/block
#define UPB     4         // units per block
#define CPB     12        // Wh columns per block (3 gates * UPB)

typedef unsigned int u32;

// ---------------------------------------------------------------------------
// Pack Wh slices: whp[blk][c][k] = Wh[k][ g*512 + blk*4 + u ]  (c = g*4+u)
// Contiguous in k so the scan kernel's wave-uniform weight reads scalarize.
// (Weights get re-fetched from L3 after each per-step buffer_inv — 24KB/blk,
// cheap and pipelined.)
// ---------------------------------------------------------------------------
__global__ __launch_bounds__(512) void prep_wh(const float* __restrict__ Wh,
                                               float* __restrict__ whp) {
    int t = blockIdx.x * 512 + threadIdx.x;      // 0 .. 786431
    int k   = t & 511;
    int cb  = t >> 9;          // blk*12 + c
    int c   = cb % 12;
    int blk = cb / 12;
    int u = c & 3, g = c >> 2;
    whp[t] = Wh[(long)k * G3 + g * HIDDEN + blk * UPB + u];
}

// ---------------------------------------------------------------------------
// Zero barrier flags with agent-scope stores (the scan polls with
// L2-bypassing loads; plain memset could leave zeros dirty in one L2).
// ---------------------------------------------------------------------------
__global__ void init_flags(unsigned* flags) {
    __hip_atomic_store(&flags[threadIdx.x], 0u, __ATOMIC_RELAXED,
                       __HIP_MEMORY_SCOPE_AGENT);
}

// ---------------------------------------------------------------------------
// xg GEMM, TRANSPOSED output: xgS[col][s][b] = emb[ids[b][s]] . Wx[:,col] + bx[col]
// so the scan's per-step gate reads are coalesced (b fastest).
// ---------------------------------------------------------------------------
__global__ __launch_bounds__(256) void xg_gemm(const int* __restrict__ ids,
                                               const float* __restrict__ emb,
                                               const float* __restrict__ Wx,
                                               const float* __restrict__ bx,
                                               float* __restrict__ xgS) {
    __shared__ float Es[64][68];   // Es[k][b], padded
    __shared__ float Ws[64][68];   // Ws[k][c], padded
    __shared__ int   sids[64];

    const int tid = threadIdx.x;
    const int nb = blockIdx.x;     // col tile 0..23
    const int s  = blockIdx.y;     // timestep 0..511
    const int tn = tid & 15;
    const int tm = tid >> 4;

    if (tid < 64) sids[tid] = ids[tid * SEQ + s];   // id for batch=tid at step s
    __syncthreads();

    float acc[4][4];               // acc[i=col][j=b]
#pragma unroll
    for (int i = 0; i < 4; ++i)
#pragma unroll
        for (int j = 0; j < 4; ++j) acc[i][j] = 0.f;

    for (int kb = 0; kb < 256; kb += 64) {
#pragma unroll
        for (int p = 0; p < 4; ++p) {
            int b = p * 16 + tm;
            float4 av = *(const float4*)(emb + (long)sids[b] * DMODEL + kb + tn * 4);
            Es[tn * 4 + 0][b] = av.x;
            Es[tn * 4 + 1][b] = av.y;
            Es[tn * 4 + 2][b] = av.z;
            Es[tn * 4 + 3][b] = av.w;
            int krow = p * 16 + tm;
            float4 wv = *(const float4*)(Wx + (long)(kb + krow) * G3 + nb * 64 + tn * 4);
            *(float4*)&Ws[krow][tn * 4] = wv;
        }
        __syncthreads();
#pragma unroll
        for (int k = 0; k < 64; ++k) {
            float4 w4 = *(const float4*)&Ws[k][tm * 4];
            float4 e4 = *(const float4*)&Es[k][tn * 4];
            float ww[4] = {w4.x, w4.y, w4.z, w4.w};
            float ee[4] = {e4.x, e4.y, e4.z, e4.w};
#pragma unroll
            for (int i = 0; i < 4; ++i)
#pragma unroll
                for (int j = 0; j < 4; ++j)
                    acc[i][j] = fmaf(ww[i], ee[j], acc[i][j]);
        }
        __syncthreads();
    }

#pragma unroll
    for (int i = 0; i < 4; ++i) {
        int col = nb * 64 + tm * 4 + i;
        float bxi = bx[col];
        float4 o;
        o.x = acc[i][0] + bxi;
        o.y = acc[i][1] + bxi;
        o.z = acc[i][2] + bxi;
        o.w = acc[i][3] + bxi;
        *(float4*)(xgS + (long)col * (SEQ * BATCH) + s * 64 + tn * 4) = o;
    }
}

// ---------------------------------------------------------------------------
// GRU scan v7: flag barrier + ONE agent-acquire fence per step + PLAIN
// pipelined float4 h loads.
// Established by R2-R6: (a) agent atomic/volatile loads serialize one per
// waitcnt (64 x ~420cyc = the 11us/step plateau of v2-v6); (b) remote sc1
// stores do NOT invalidate local L2, so plain loads without a fence read
// stale data (v6). The memory-model-correct fix: after the flag barrier,
// wave 0 executes __builtin_amdgcn_fence(ACQUIRE, "agent") — buffer_inv of
// the CU's L1 / XCD's L2 (once per block per step, NOT per poll iteration —
// that was R1's 40us/step mistake). After __syncthreads, all waves issue
// plain float4 loads: fully pipelined, fresh from L3.
// h layout hQ[q][b][4] (quad of consecutive k per lane) so each lane reads
// its 64 k-values as 16 global_load_dwordx4. A block's 4 units are exactly
// one quad (j = blk*4+gu -> q = blk, e = gu).
// Ordering: producer sc1 h-stores drained by sync2's vmcnt(0) before the
// flag store (release); consumer poll -> acquire fence -> sync3 -> loads.
// Deadlock-free: 128 blocks co-resident (<=256 CUs, one kernel).
// ---------------------------------------------------------------------------
__global__ __launch_bounds__(512, 2) void gru_scan(const float* __restrict__ whp,
                                                   const float* __restrict__ xgS,
                                                   const float* __restrict__ bh,
                                                   float* hbuf,
                                                   unsigned* flags) {
    const int tid = threadIdx.x;
    const int blk = blockIdx.x;
    const int b   = tid & 63;                                 // lane = batch
    const int wu  = __builtin_amdgcn_readfirstlane(tid >> 6); // wave 0..7

    __shared__ float part[8][CPB][64];   // 24 KB partial sums
    __shared__ float hl[UPB][64];        // this block's own h slice (hprev)

    const float* wb = whp + blk * (CPB * HIDDEN) + wu * 64;   // + c*512 + k

    const int gu = tid >> 6;
    int jg = 0;
    float bhr = 0.f, bhz = 0.f, bhn = 0.f;
    const float* xr_p = nullptr; const float* xz_p = nullptr; const float* xn_p = nullptr;
    if (tid < 256) {
        jg  = blk * UPB + gu;
        bhr = bh[jg];
        bhz = bh[HIDDEN + jg];
        bhn = bh[2 * HIDDEN + jg];
        xr_p = xgS + (long)jg * (SEQ * BATCH) + b;
        xz_p = xgS + (long)(HIDDEN + jg) * (SEQ * BATCH) + b;
        xn_p = xgS + (long)(2 * HIDDEN + jg) * (SEQ * BATCH) + b;
        hl[gu][b] = 0.f;                 // h0 = 0
    }
    __syncthreads();

#pragma unroll 1
    for (int t = 0; t < SEQ; ++t) {
        float* hq_cur = hbuf + (t & 1) * (HIDDEN * BATCH);
        float* hq_nxt = hbuf + ((t + 1) & 1) * (HIDDEN * BATCH);

        // coalesced gate-input loads (xgS[col][t][b]); refetched from L3
        // after the inv — 3 coalesced lines per wave, pipelined
        float xr = 0.f, xz = 0.f, xn = 0.f, hprev = 0.f;
        if (tid < 256) {
            xr = xr_p[t * 64];
            xz = xz_p[t * 64];
            xn = xn_p[t * 64];
            hprev = hl[gu][b];
        }

        if (t > 0) {
            // PLAIN pipelined bulk load: 16 x global_load_dwordx4 per lane,
            // one waitcnt at first use. Freshness: acquire fence last step.
            const float4* hq4 = (const float4*)hq_cur + (wu * 16) * 64 + b;
            float4 hv[16];
#pragma unroll
            for (int i = 0; i < 16; ++i)
                hv[i] = hq4[(long)i * 64];

            float acc[CPB];
#pragma unroll
            for (int c = 0; c < CPB; ++c) acc[c] = 0.f;
#pragma unroll
            for (int i = 0; i < 16; ++i) {
                const float he[4] = {hv[i].x, hv[i].y, hv[i].z, hv[i].w};
#pragma unroll
                for (int e = 0; e < 4; ++e) {
                    const float hvv = he[e];
                    const int kk = i * 4 + e;
#pragma unroll
                    for (int c = 0; c < CPB; ++c)
                        acc[c] = fmaf(hvv, wb[c * HIDDEN + kk], acc[c]);
                }
            }
#pragma unroll
            for (int c = 0; c < CPB; ++c) part[wu][c][b] = acc[c];
        } else {
            // h0 == 0 => hg = bh
#pragma unroll
            for (int c = 0; c < CPB; ++c) part[wu][c][b] = 0.f;
        }
        __syncthreads();                                   // sync1: partials ready

        if (tid < 256) {
            float hgr = bhr, hgz = bhz, hgn = bhn;
#pragma unroll
            for (int ww = 0; ww < 8; ++ww) {
                hgr += part[ww][gu][b];
                hgz += part[ww][4 + gu][b];
                hgn += part[ww][8 + gu][b];
            }
            float r  = 1.f / (1.f + expf(-(xr + hgr)));
            float z  = 1.f / (1.f + expf(-(xz + hgz)));
            float nn = tanhf(xn + r * hgn);
            float hnew = (1.f - z) * nn + z * hprev;
            // write-through to the coherence point (L3); quad layout:
            // unit j = blk*4+gu  ->  hQ[blk][b][gu]
            __hip_atomic_store(&hq_nxt[(blk * 64 + b) * 4 + gu], hnew,
                               __ATOMIC_RELAXED, __HIP_MEMORY_SCOPE_AGENT);
            hl[gu][b] = hnew;
        }
        __syncthreads();                                   // sync2: drains h stores

        if (t < SEQ - 1) {
            if (tid == 0)
                __hip_atomic_store(&flags[blk], (unsigned)(t + 1),
                                   __ATOMIC_RELAXED, __HIP_MEMORY_SCOPE_AGENT);
            if (wu == 0) {
                // the ONLY polling wave in this block
                const unsigned tgt = (unsigned)(t + 1);
                for (;;) {
                    unsigned f0 = __hip_atomic_load(&flags[b], __ATOMIC_RELAXED,
                                                    __HIP_MEMORY_SCOPE_AGENT);
                    unsigned f1 = __hip_atomic_load(&flags[64 + b], __ATOMIC_RELAXED,
                                                    __HIP_MEMORY_SCOPE_AGENT);
                    if (__all(f0 >= tgt && f1 >= tgt)) break;
                    __builtin_amdgcn_s_sleep(1);
                }
                // ONE acquire per block per step: invalidates stale L1/L2
                // lines so the next bulk read's plain loads are fresh.
                __builtin_amdgcn_fence(__ATOMIC_ACQUIRE, "agent");
            }
            __syncthreads();                               // sync3: release
        }
    }
}

// ---------------------------------------------------------------------------
// head: logits[b][n] = sum_k h[k][b] * Wo[k][n] + bo[n]
// Final h (t=512) sits in slot 0 of hbuf, quad layout hQ[k>>2][b][k&3].
// ---------------------------------------------------------------------------
__global__ void head_kernel(const float* __restrict__ hT,
                            const float* __restrict__ Wo,
                            const float* __restrict__ bo,
                            float* __restrict__ out) {
    int tid = threadIdx.x;        // 128 threads
    int b = tid >> 1, n = tid & 1;
    float acc = bo[n];
#pragma unroll 8
    for (int k = 0; k < HIDDEN; ++k)
        acc = fmaf(hT[((k >> 2) * 64 + b) * 4 + (k & 3)], Wo[k * 2 + n], acc);
    out[b * 2 + n] = acc;
}

// ---------------------------------------------------------------------------
extern "C" void kernel_launch(void* const* d_in, const int* in_sizes, int n_in,
                              void* d_out, int out_size, void* d_ws, size_t ws_size,
                              hipStream_t stream) {
    (void)in_sizes; (void)n_in; (void)out_size; (void)ws_size;
    const int*   ids = (const int*)  d_in[0];
    const float* emb = (const float*)d_in[1];
    const float* Wx  = (const float*)d_in[2];
    const float* Wh  = (const float*)d_in[3];
    const float* bx  = (const float*)d_in[4];
    const float* bh  = (const float*)d_in[5];
    const float* Wo  = (const float*)d_in[6];
    const float* bo  = (const float*)d_in[7];
    float* out = (float*)d_out;

    char* ws = (char*)d_ws;
    // ws layout: [flags 1KB][hbuf 2*512*64 f32 = 256KB][whp 3MB][xgS 201MB]
    // hbuf needs no init: t=0 skips the matvec (h0=0 handled analytically).
    unsigned* flags = (unsigned*)ws;
    float* hbuf = (float*)(ws + 1024);
    float* whp  = (float*)(ws + 1024 + 2 * HIDDEN * BATCH * 4);
    float* xgS  = (float*)(ws + 1024 + 2 * HIDDEN * BATCH * 4 + NBLK * CPB * HIDDEN * 4);

    init_flags<<<dim3(1), dim3(NBLK), 0, stream>>>(flags);
    prep_wh<<<dim3(1536), dim3(512), 0, stream>>>(Wh, whp);
    xg_gemm<<<dim3(24, 512), dim3(256), 0, stream>>>(ids, emb, Wx, bx, xgS);
    gru_scan<<<dim3(NBLK), dim3(512), 0, stream>>>(whp, xgS, bh, hbuf, flags);
    head_kernel<<<dim3(1), dim3(128), 0, stream>>>(hbuf, Wo, bo, out);
}

// Round 8
// 5607.548 us; speedup vs baseline: 2.1648x; 1.1176x over previous
//
#include <hip/hip_runtime.h>
#include <hip/hip_bf16.h>

// Problem constants
#define BATCH   64
#define SEQ     512
#define DMODEL  256
#define HIDDEN  512
#define G3      1536      // 3*HIDDEN
#define NBLK    128       // scan blocks; 512 hidden units / 128 = 4 units/block
#define UPB     4         // units per block
#define CPB     12        // Wh columns per block (3 gates * UPB)
#define CHUNK   128       // timesteps per scan chunk-kernel
#define NCHUNK  4         // SEQ / CHUNK
#define HSLOT   (HIDDEN * BATCH)   // floats per h slot (128 KB)

typedef unsigned long long u64;
typedef unsigned int u32;

// ---------------------------------------------------------------------------
// Pack Wh slices: whp[blk][c][k] = Wh[k][ g*512 + blk*4 + u ]  (c = g*4+u)
// Contiguous in k -> wave-uniform weight reads scalarize (s_load). With no
// invalidation anywhere in the scan loop, each block's 24 KB slice stays
// L2-hot for the whole chunk.
// ---------------------------------------------------------------------------
__global__ __launch_bounds__(512) void prep_wh(const float* __restrict__ Wh,
                                               float* __restrict__ whp) {
    int t = blockIdx.x * 512 + threadIdx.x;      // 0 .. 786431
    int k   = t & 511;
    int cb  = t >> 9;          // blk*12 + c
    int c   = cb % 12;
    int blk = cb / 12;
    int u = c & 3, g = c >> 2;
    whp[t] = Wh[(long)k * G3 + g * HIDDEN + blk * UPB + u];
}

// ---------------------------------------------------------------------------
// Zero barrier flags with agent-scope stores (the scan polls with
// L2-bypassing loads). Flags are monotonic global-step values across all
// 4 chunk kernels, so they are initialized exactly once per launch.
// ---------------------------------------------------------------------------
__global__ void init_flags(unsigned* flags) {
    __hip_atomic_store(&flags[threadIdx.x], 0u, __ATOMIC_RELAXED,
                       __HIP_MEMORY_SCOPE_AGENT);
}

// ---------------------------------------------------------------------------
// Chunked xg GEMM: xgC[col][lt][b] = emb[ids[b][s]] . Wx[:,col] + bx[col],
// s = chunk*CHUNK + lt. One 50 MB buffer reused per chunk; the consumer
// scan is a later kernel launch (entry-acquire) so reuse is coherent.
// ---------------------------------------------------------------------------
__global__ __launch_bounds__(256) void xg_gemm(const int* __restrict__ ids,
                                               const float* __restrict__ emb,
                                               const float* __restrict__ Wx,
                                               const float* __restrict__ bx,
                                               float* __restrict__ xgC,
                                               int chunk) {
    __shared__ float Es[64][68];   // Es[k][b], padded
    __shared__ float Ws[64][68];   // Ws[k][c], padded
    __shared__ int   sids[64];

    const int tid = threadIdx.x;
    const int nb = blockIdx.x;     // col tile 0..23
    const int lt = blockIdx.y;     // local timestep 0..127
    const int s  = chunk * CHUNK + lt;
    const int tn = tid & 15;
    const int tm = tid >> 4;

    if (tid < 64) sids[tid] = ids[tid * SEQ + s];   // id for batch=tid, step s
    __syncthreads();

    float acc[4][4];               // acc[i=col][j=b]
#pragma unroll
    for (int i = 0; i < 4; ++i)
#pragma unroll
        for (int j = 0; j < 4; ++j) acc[i][j] = 0.f;

    for (int kb = 0; kb < 256; kb += 64) {
#pragma unroll
        for (int p = 0; p < 4; ++p) {
            int b = p * 16 + tm;
            float4 av = *(const float4*)(emb + (long)sids[b] * DMODEL + kb + tn * 4);
            Es[tn * 4 + 0][b] = av.x;
            Es[tn * 4 + 1][b] = av.y;
            Es[tn * 4 + 2][b] = av.z;
            Es[tn * 4 + 3][b] = av.w;
            int krow = p * 16 + tm;
            float4 wv = *(const float4*)(Wx + (long)(kb + krow) * G3 + nb * 64 + tn * 4);
            *(float4*)&Ws[krow][tn * 4] = wv;
        }
        __syncthreads();
#pragma unroll
        for (int k = 0; k < 64; ++k) {
            float4 w4 = *(const float4*)&Ws[k][tm * 4];
            float4 e4 = *(const float4*)&Es[k][tn * 4];
            float ww[4] = {w4.x, w4.y, w4.z, w4.w};
            float ee[4] = {e4.x, e4.y, e4.z, e4.w};
#pragma unroll
            for (int i = 0; i < 4; ++i)
#pragma unroll
                for (int j = 0; j < 4; ++j)
                    acc[i][j] = fmaf(ww[i], ee[j], acc[i][j]);
        }
        __syncthreads();
    }

#pragma unroll
    for (int i = 0; i < 4; ++i) {
        int col = nb * 64 + tm * 4 + i;
        float bxi = bx[col];
        float4 o;
        o.x = acc[i][0] + bxi;
        o.y = acc[i][1] + bxi;
        o.z = acc[i][2] + bxi;
        o.w = acc[i][3] + bxi;
        *(float4*)(xgC + (long)col * (CHUNK * BATCH) + lt * 64 + tn * 4) = o;
    }
}

// ---------------------------------------------------------------------------
// GRU scan v8: rotating 128-slot h history -> PLAIN cached consumer loads.
// Law from R2-R7: reads that must be made coherent at read-time (atomic /
// volatile / post-buffer_inv refill) serialize into ~10us/step latency
// chains. Here each h[t] lives at a FRESH slot (t mod 128): within one
// chunk kernel no cache can hold a pre-write copy of an address that was
// never touched before its single write, so consumer reads are plain
// float4 loads (pipelined, L3-served) and weights/xg stay L2-hot (no inv).
// Slot reuse across chunks is safe: chunks are separate kernel launches
// (entry acquire invalidates L1/L2, exit release writes back).
// Producers: sc1 write-through (u64 pairs), drained by the pre-barrier
// vmcnt(0) at sync C, then v4's single-poller monotonic flag barrier.
// Deadlock-free: 128 blocks co-resident (<=256 CUs, one kernel at a time).
// h slot layout (quads): slot[q][b][e]  (q=unit>>2=blk, e=unit&3)
// -> consumer lane b reads 16 x global_load_dwordx4; producer writes 2 x
//    u64 per lane pair (full 16B sectors, no partial-write amplification).
// ---------------------------------------------------------------------------
__global__ __launch_bounds__(512, 2) void gru_scan(const float* __restrict__ whp,
                                                   const float* __restrict__ xgC,
                                                   const float* __restrict__ bh,
                                                   float* hist,
                                                   unsigned* flags,
                                                   int chunk) {
    const int tid = threadIdx.x;
    const int blk = blockIdx.x;
    const int b   = tid & 63;                                 // lane = batch
    const int wu  = __builtin_amdgcn_readfirstlane(tid >> 6); // wave 0..7

    __shared__ float part[8][CPB][64];   // 24 KB partial sums
    __shared__ float hl[UPB][64];        // this block's own h slice

    const float* wb = whp + blk * (CPB * HIDDEN) + wu * 64;   // + c*512 + k
    const int base = chunk * CHUNK;

    const int gu = tid >> 6;
    int jg = 0;
    float bhr = 0.f, bhz = 0.f, bhn = 0.f;
    const float* xr_p = nullptr; const float* xz_p = nullptr; const float* xn_p = nullptr;
    if (tid < 256) {
        jg  = blk * UPB + gu;
        bhr = bh[jg];
        bhz = bh[HIDDEN + jg];
        bhn = bh[2 * HIDDEN + jg];
        xr_p = xgC + (long)jg * (CHUNK * BATCH) + b;
        xz_p = xgC + (long)(HIDDEN + jg) * (CHUNK * BATCH) + b;
        xn_p = xgC + (long)(2 * HIDDEN + jg) * (CHUNK * BATCH) + b;
        // slot 0 holds h[base] (written by previous chunk kernel; fresh via
        // kernel-entry acquire). Chunk 0: h0 = 0.
        hl[gu][b] = (chunk == 0) ? 0.f
                                 : hist[(long)blk * 256 + b * 4 + gu];
    }
    __syncthreads();

#pragma unroll 1
    for (int lt = 0; lt < CHUNK; ++lt) {
        const int t = base + lt;
        const float* hs = hist + (long)lt * HSLOT;                     // h[t]
        float*       hw = hist + (long)((lt + 1) & (CHUNK - 1)) * HSLOT; // h[t+1]

        // gate inputs: plain cached loads (xgC stays L1/L2-hot)
        float xr = 0.f, xz = 0.f, xn = 0.f, hprev = 0.f;
        if (tid < 256) {
            xr = xr_p[lt * 64];
            xz = xz_p[lt * 64];
            xn = xn_p[lt * 64];
            hprev = hl[gu][b];
        }

        if (t > 0) {
            // PLAIN pipelined bulk read of h[t]: 16 x dwordx4 per lane.
            const float4* hq4 = (const float4*)hs + (wu * 16) * 64 + b;
            float4 hv[16];
#pragma unroll
            for (int i = 0; i < 16; ++i)
                hv[i] = hq4[(long)i * 64];

            float acc[CPB];
#pragma unroll
            for (int c = 0; c < CPB; ++c) acc[c] = 0.f;
#pragma unroll
            for (int i = 0; i < 16; ++i) {
                const float he[4] = {hv[i].x, hv[i].y, hv[i].z, hv[i].w};
#pragma unroll
                for (int e = 0; e < 4; ++e) {
                    const float hvv = he[e];
                    const int kk = i * 4 + e;
#pragma unroll
                    for (int c = 0; c < CPB; ++c)
                        acc[c] = fmaf(hvv, wb[c * HIDDEN + kk], acc[c]);
                }
            }
#pragma unroll
            for (int c = 0; c < CPB; ++c) part[wu][c][b] = acc[c];
        } else {
            // h0 == 0 => hg = bh
#pragma unroll
            for (int c = 0; c < CPB; ++c) part[wu][c][b] = 0.f;
        }
        __syncthreads();                               // A: partials ready

        if (tid < 256) {
            float hgr = bhr, hgz = bhz, hgn = bhn;
#pragma unroll
            for (int ww = 0; ww < 8; ++ww) {
                hgr += part[ww][gu][b];
                hgz += part[ww][4 + gu][b];
                hgn += part[ww][8 + gu][b];
            }
            float r  = 1.f / (1.f + expf(-(xr + hgr)));
            float z  = 1.f / (1.f + expf(-(xz + hgz)));
            float nn = tanhf(xn + r * hgn);
            hl[gu][b] = (1.f - z) * nn + z * hprev;
        }
        __syncthreads();                               // B: hl ready

        // producers: 128 threads store the block's 4 units as u64 pairs,
        // sc1 write-through to the coherence point (full 16B sectors).
        if (tid < 128) {
            const int p = tid >> 6;                    // pair 0..1
            u32 lo = __float_as_uint(hl[2 * p][b]);
            u32 hi = __float_as_uint(hl[2 * p + 1][b]);
            u64 pk = ((u64)hi << 32) | (u64)lo;
            __hip_atomic_store((u64*)(hw + (long)blk * 256 + b * 4 + 2 * p), pk,
                               __ATOMIC_RELAXED, __HIP_MEMORY_SCOPE_AGENT);
        }

        if (lt < CHUNK - 1) {
            __syncthreads();                           // C: drains h stores
            if (tid == 0)
                __hip_atomic_store(&flags[blk], (u32)(t + 1),
                                   __ATOMIC_RELAXED, __HIP_MEMORY_SCOPE_AGENT);
            if (wu == 0) {
                // the ONLY polling wave in this block
                const u32 tgt = (u32)(t + 1);
                for (;;) {
                    u32 f0 = __hip_atomic_load(&flags[b], __ATOMIC_RELAXED,
                                               __HIP_MEMORY_SCOPE_AGENT);
                    u32 f1 = __hip_atomic_load(&flags[64 + b], __ATOMIC_RELAXED,
                                               __HIP_MEMORY_SCOPE_AGENT);
                    if (__all(f0 >= tgt && f1 >= tgt)) break;
                    __builtin_amdgcn_s_sleep(1);
                }
            }
            __syncthreads();                           // D: release
        }
        // lt == CHUNK-1: kernel ends; exit release + next kernel's entry
        // acquire replace the barrier.
    }
}

// ---------------------------------------------------------------------------
// head: logits[b][n] = sum_k h[k][b] * Wo[k][n] + bo[n]
// h[512] sits in hist slot 0 (written by chunk 3's last step), quad layout.
// ---------------------------------------------------------------------------
__global__ void head_kernel(const float* __restrict__ hist,
                            const float* __restrict__ Wo,
                            const float* __restrict__ bo,
                            float* __restrict__ out) {
    int tid = threadIdx.x;        // 128 threads
    int b = tid >> 1, n = tid & 1;
    float acc = bo[n];
#pragma unroll 8
    for (int k = 0; k < HIDDEN; ++k)
        acc = fmaf(hist[(k >> 2) * 256 + b * 4 + (k & 3)], Wo[k * 2 + n], acc);
    out[b * 2 + n] = acc;
}

// ---------------------------------------------------------------------------
extern "C" void kernel_launch(void* const* d_in, const int* in_sizes, int n_in,
                              void* d_out, int out_size, void* d_ws, size_t ws_size,
                              hipStream_t stream) {
    (void)in_sizes; (void)n_in; (void)out_size; (void)ws_size;
    const int*   ids = (const int*)  d_in[0];
    const float* emb = (const float*)d_in[1];
    const float* Wx  = (const float*)d_in[2];
    const float* Wh  = (const float*)d_in[3];
    const float* bx  = (const float*)d_in[4];
    const float* bh  = (const float*)d_in[5];
    const float* Wo  = (const float*)d_in[6];
    const float* bo  = (const float*)d_in[7];
    float* out = (float*)d_out;

    char* ws = (char*)d_ws;
    // ws layout: [flags 1KB][hist 16MB][whp 3MB][xgC 50.3MB]  (~70 MB total)
    // hist needs NO init: every slot is written before it is read in every
    // kernel that reads it (chunk0/lt0 skips the read analytically).
    unsigned* flags = (unsigned*)ws;
    float* hist = (float*)(ws + 1024);
    float* whp  = (float*)(ws + 1024 + (size_t)CHUNK * HSLOT * 4);
    float* xgC  = (float*)(ws + 1024 + (size_t)CHUNK * HSLOT * 4
                           + (size_t)NBLK * CPB * HIDDEN * 4);

    init_flags<<<dim3(1), dim3(NBLK), 0, stream>>>(flags);
    prep_wh<<<dim3(1536), dim3(512), 0, stream>>>(Wh, whp);
    for (int c = 0; c < NCHUNK; ++c) {
        xg_gemm<<<dim3(24, CHUNK), dim3(256), 0, stream>>>(ids, emb, Wx, bx, xgC, c);
        gru_scan<<<dim3(NBLK), dim3(512), 0, stream>>>(whp, xgC, bh, hist, flags, c);
    }
    head_kernel<<<dim3(1), dim3(128), 0, stream>>>(hist, Wo, bo, out);
}